// Round 1
// baseline (2303.236 us; speedup 1.0000x reference)
//
#include <hip/hip_runtime.h>
#include <hip/hip_bf16.h>

using short8  = __attribute__((ext_vector_type(8))) short;
using floatx4 = __attribute__((ext_vector_type(4))) float;
typedef unsigned short u16;

#define DEVINL static __device__ __forceinline__

constexpr int kB = 512;    // batch
constexpr int kH = 1024;   // hidden
constexpr int kO = 256;    // output dim
constexpr int kT = 128;    // timesteps
constexpr int kG = 4096;   // 4*H gate columns

DEVINL u16 f2bf(float x) {
  union { float f; unsigned u; } v; v.f = x;
  unsigned r = v.u + 0x7fffu + ((v.u >> 16) & 1u);   // RNE
  return (u16)(r >> 16);
}
DEVINL float sigm(float x)  { return 1.0f / (1.0f + __expf(-x)); }
DEVINL float tanhx(float x) { return 1.0f - 2.0f / (__expf(2.0f * x) + 1.0f); }

DEVINL void gload16(const void* src, void* ldsbase) {
  __builtin_amdgcn_global_load_lds((__attribute__((address_space(1))) void*)(char*)src,
                                   (__attribute__((address_space(3))) void*)ldsbase,
                                   16, 0, 0);
}
DEVINL short8 lds8(const void* p) { return *(const short8*)p; }

// ---------------- prep kernels ----------------

// c = 0, Hbuf[0] = bf16(encoder_hidden)
__global__ void k_init(const float* __restrict__ enc, float* __restrict__ c,
                       u16* __restrict__ h0) {
  int i = blockIdx.x * 256 + threadIdx.x;
  c[i]  = 0.0f;
  h0[i] = f2bf(enc[i]);
}

// bias0 = b_ih + b_hh ; bias1 = bias0 + W_ih @ b_out
__global__ void k_bias(const float* __restrict__ bih, const float* __restrict__ bhh,
                       const float* __restrict__ Wih, const float* __restrict__ bout,
                       float* __restrict__ bias0, float* __restrict__ bias1) {
  int n = blockIdx.x * 256 + threadIdx.x;        // 0..4095
  float b0 = bih[n] + bhh[n];
  const float* row = Wih + (long)n * 256;
  float s = 0.f;
  for (int j = 0; j < 256; ++j) s += row[j] * bout[j];
  bias0[n] = b0;
  bias1[n] = b0 + s;
}

// Wt0[r(n,g)][k] = bf16(W_hh[g*1024+n][k]);  r(n,g) = (n>>4)*64 + g*16 + (n&15)
__global__ void k_w0(const float* __restrict__ Whh, u16* __restrict__ Wt0) {
  const int r = blockIdx.x;                       // 4096 rows
  const int k = threadIdx.x * 4;                  // 256 thr * 4 = 1024
  const int n = ((r >> 6) << 4) | (r & 15);
  const int g = (r >> 4) & 3;
  const float4 v = *(const float4*)(Whh + (long)(g * 1024 + n) * 1024 + k);
  ushort4 o; o.x = f2bf(v.x); o.y = f2bf(v.y); o.z = f2bf(v.z); o.w = f2bf(v.w);
  *(ushort4*)(Wt0 + (long)r * 1024 + k) = o;
}

// Wob = bf16(W_out)  (256 x 1024, row-major: o-major, k-contiguous)
__global__ void k_wo(const float* __restrict__ Wout, u16* __restrict__ Wob) {
  const long i = ((long)blockIdx.x * 256 + threadIdx.x) * 4;   // 262144 elems
  const float4 v = *(const float4*)(Wout + i);
  ushort4 o; o.x = f2bf(v.x); o.y = f2bf(v.y); o.z = f2bf(v.z); o.w = f2bf(v.w);
  *(ushort4*)(Wob + i) = o;
}

// Wt1[r(n,g)][k] = bf16( W_hh[g*1024+n][k] + sum_j W_out[j][k]*W_ih[g*1024+n][j] )
__global__ __launch_bounds__(256) void k_w1(
    const float* __restrict__ Wih, const float* __restrict__ Wout,
    const float* __restrict__ Whh, u16* __restrict__ Wt1) {
  __shared__ float sW[16][256];
  const int g = blockIdx.x & 3, n16 = blockIdx.x >> 2;   // 4 gates x 64 groups
  const int tid = threadIdx.x;
#pragma unroll
  for (int nl = 0; nl < 16; ++nl)
    sW[nl][tid] = Wih[(long)(g * 1024 + n16 * 16 + nl) * 256 + tid];
  __syncthreads();
  const int k4 = tid * 4;
  float acc[16][4];
#pragma unroll
  for (int nl = 0; nl < 16; ++nl)
#pragma unroll
    for (int q = 0; q < 4; ++q) acc[nl][q] = 0.f;
  for (int j = 0; j < 256; ++j) {
    const float4 wo = *(const float4*)(Wout + (long)j * 1024 + k4);
#pragma unroll
    for (int nl = 0; nl < 16; ++nl) {
      const float w = sW[nl][j];
      acc[nl][0] += w * wo.x; acc[nl][1] += w * wo.y;
      acc[nl][2] += w * wo.z; acc[nl][3] += w * wo.w;
    }
  }
#pragma unroll
  for (int nl = 0; nl < 16; ++nl) {
    const int n = n16 * 16 + nl;
    const int rout = n16 * 64 + g * 16 + nl;
    const float* hh = Whh + (long)(g * 1024 + n) * 1024 + k4;
    ushort4 o;
    o.x = f2bf(hh[0] + acc[nl][0]); o.y = f2bf(hh[1] + acc[nl][1]);
    o.z = f2bf(hh[2] + acc[nl][2]); o.w = f2bf(hh[3] + acc[nl][3]);
    *(ushort4*)(Wt1 + (long)rout * 1024 + k4) = o;
  }
}

// ---------------- main recurrence step ----------------
// gates(512 x 4096) = Xprev(512x1024,bf16) @ Wt^T  (Wt is n-major: [4096][1024])
// fused LSTM cell epilogue -> c (fp32, in place), Hnext (bf16)
__global__ __launch_bounds__(256) void k_step(
    const u16* __restrict__ Xprev, u16* __restrict__ Hnext,
    float* __restrict__ c, const u16* __restrict__ Wt,
    const float* __restrict__ bias) {
  __shared__ u16 As[64 * 64];    // [row64][k64] bf16, XOR-swizzled, 8 KB
  __shared__ u16 Bs[128 * 64];   // [col128][k64] bf16, XOR-swizzled, 16 KB

  const int tid  = threadIdx.x;
  const int lane = tid & 63;
  const int wid  = tid >> 6;
  const int wr   = wid >> 1;            // wave row 0..1  (32 rows each)
  const int wc   = wid & 1;             // wave col 0..1  (16-hidden group each)
  const int n0   = blockIdx.x * 32;     // hidden base
  const int m0   = blockIdx.y * 64;     // batch-row base
  const long wrow0 = (long)n0 * 4;      // Wt row base (128 interleaved rows)
  const int hi  = lane >> 4;            // 0..3
  const int l15 = lane & 15;

  floatx4 acc[2][4];
#pragma unroll
  for (int a2 = 0; a2 < 2; ++a2)
#pragma unroll
    for (int f = 0; f < 4; ++f)
#pragma unroll
      for (int r = 0; r < 4; ++r) acc[a2][f][r] = 0.0f;

  for (int kt = 0; kt < 16; ++kt) {
    const int kb = kt * 128;            // k byte offset (64 bf16 per tile)
    // stage A: 64 rows x 128 B, linear LDS dest + inverse-swizzled global src
#pragma unroll
    for (int i = 0; i < 2; ++i) {
      const int u = i * 256 + tid;
      const int row = u >> 3;
      const int off = (u & 7) * 16;
      const char* src = (const char*)Xprev + ((long)(m0 + row) << 11) + kb +
                        (off ^ ((row & 7) << 4));
      gload16(src, (char*)As + (i * 256 + wid * 64) * 16);
    }
    // stage B: 128 cols x 128 B
#pragma unroll
    for (int i = 0; i < 4; ++i) {
      const int u = i * 256 + tid;
      const int col = u >> 3;
      const int off = (u & 7) * 16;
      const char* src = (const char*)Wt + ((wrow0 + col) << 11) + kb +
                        (off ^ ((col & 7) << 4));
      gload16(src, (char*)Bs + (i * 256 + wid * 64) * 16);
    }
    __syncthreads();
#pragma unroll
    for (int ks = 0; ks < 2; ++ks) {
      const int kbyte = ks * 64 + hi * 16;
      const int ra = wr * 32 + l15;
      short8 a0 = lds8((const char*)As + ra * 128 + (kbyte ^ ((ra & 7) << 4)));
      const int rb = ra + 16;
      short8 a1 = lds8((const char*)As + rb * 128 + (kbyte ^ ((rb & 7) << 4)));
#pragma unroll
      for (int f = 0; f < 4; ++f) {
        const int colx = wc * 64 + f * 16 + l15;
        short8 b = lds8((const char*)Bs + colx * 128 + (kbyte ^ ((colx & 7) << 4)));
        acc[0][f] = __builtin_amdgcn_mfma_f32_16x16x32_bf16(a0, b, acc[0][f], 0, 0, 0);
        acc[1][f] = __builtin_amdgcn_mfma_f32_16x16x32_bf16(a1, b, acc[1][f], 0, 0, 0);
      }
    }
    __syncthreads();
  }

  // fused LSTM cell: lane holds i,f,g,o for the same (row, n) in acc[.][0..3]
  const int n_glob = n0 + wc * 16 + l15;
  const float bi = bias[n_glob];
  const float bf = bias[1024 + n_glob];
  const float bg = bias[2048 + n_glob];
  const float bo = bias[3072 + n_glob];
#pragma unroll
  for (int a2 = 0; a2 < 2; ++a2) {
#pragma unroll
    for (int r = 0; r < 4; ++r) {
      const int row = m0 + wr * 32 + a2 * 16 + hi * 4 + r;
      const long ci = (long)row * kH + n_glob;
      const float iv = sigm(acc[a2][0][r] + bi);
      const float fv = sigm(acc[a2][1][r] + bf);
      const float gv = tanhx(acc[a2][2][r] + bg);
      const float ov = sigm(acc[a2][3][r] + bo);
      const float cn = fv * c[ci] + iv * gv;
      c[ci] = cn;
      Hnext[ci] = f2bf(ov * tanhx(cn));
    }
  }
}

// ---------------- prediction head ----------------
// out[b][t][o] = Hbuf[(t+1)%nsl][b][:] @ Wob[o][:] + b_out[o]
__global__ __launch_bounds__(256) void k_pred(
    const u16* __restrict__ Hbuf, long HS, int nsl,
    const u16* __restrict__ Wob, const float* __restrict__ b_out,
    float* __restrict__ out, int t0) {
  __shared__ u16 As[64 * 64];
  __shared__ u16 Bs[128 * 64];
  const int t = t0 + blockIdx.z;
  const u16* Hm = Hbuf + (long)((t + 1) % nsl) * HS;

  const int tid = threadIdx.x, lane = tid & 63, wid = tid >> 6;
  const int wr = wid >> 1, wc = wid & 1;
  const int m0 = blockIdx.y * 64;
  const int o0 = blockIdx.x * 128;
  const int hi = lane >> 4, l15 = lane & 15;

  floatx4 acc[2][4];
#pragma unroll
  for (int a2 = 0; a2 < 2; ++a2)
#pragma unroll
    for (int f = 0; f < 4; ++f)
#pragma unroll
      for (int r = 0; r < 4; ++r) acc[a2][f][r] = 0.0f;

  for (int kt = 0; kt < 16; ++kt) {
    const int kb = kt * 128;
#pragma unroll
    for (int i = 0; i < 2; ++i) {
      const int u = i * 256 + tid;
      const int row = u >> 3;
      const int off = (u & 7) * 16;
      const char* src = (const char*)Hm + ((long)(m0 + row) << 11) + kb +
                        (off ^ ((row & 7) << 4));
      gload16(src, (char*)As + (i * 256 + wid * 64) * 16);
    }
#pragma unroll
    for (int i = 0; i < 4; ++i) {
      const int u = i * 256 + tid;
      const int col = u >> 3;
      const int off = (u & 7) * 16;
      const char* src = (const char*)Wob + ((long)(o0 + col) << 11) + kb +
                        (off ^ ((col & 7) << 4));
      gload16(src, (char*)Bs + (i * 256 + wid * 64) * 16);
    }
    __syncthreads();
#pragma unroll
    for (int ks = 0; ks < 2; ++ks) {
      const int kbyte = ks * 64 + hi * 16;
      const int ra = wr * 32 + l15;
      short8 a0 = lds8((const char*)As + ra * 128 + (kbyte ^ ((ra & 7) << 4)));
      const int rb = ra + 16;
      short8 a1 = lds8((const char*)As + rb * 128 + (kbyte ^ ((rb & 7) << 4)));
#pragma unroll
      for (int f = 0; f < 4; ++f) {
        const int colx = wc * 64 + f * 16 + l15;
        short8 b = lds8((const char*)Bs + colx * 128 + (kbyte ^ ((colx & 7) << 4)));
        acc[0][f] = __builtin_amdgcn_mfma_f32_16x16x32_bf16(a0, b, acc[0][f], 0, 0, 0);
        acc[1][f] = __builtin_amdgcn_mfma_f32_16x16x32_bf16(a1, b, acc[1][f], 0, 0, 0);
      }
    }
    __syncthreads();
  }

#pragma unroll
  for (int f = 0; f < 4; ++f) {
    const int o = o0 + wc * 64 + f * 16 + l15;
    const float bb = b_out[o];
#pragma unroll
    for (int a2 = 0; a2 < 2; ++a2)
#pragma unroll
      for (int r = 0; r < 4; ++r) {
        const int row = m0 + wr * 32 + a2 * 16 + hi * 4 + r;
        out[((long)row * kT + t) * kO + o] = acc[a2][f][r] + bb;
      }
  }
}

// ---------------- launcher ----------------
extern "C" void kernel_launch(void* const* d_in, const int* in_sizes, int n_in,
                              void* d_out, int out_size, void* d_ws, size_t ws_size,
                              hipStream_t stream) {
  const float* enc  = (const float*)d_in[0];
  // d_in[1] = target_length (always 128 here)
  const float* Wih  = (const float*)d_in[2];
  const float* Whh  = (const float*)d_in[3];
  const float* bih  = (const float*)d_in[4];
  const float* bhh  = (const float*)d_in[5];
  const float* Wout = (const float*)d_in[6];
  const float* bout = (const float*)d_in[7];
  float* out = (float*)d_out;
  char*  ws  = (char*)d_ws;

  size_t off = 0;
  auto take = [&](size_t bytes) {
    size_t o = off; off += (bytes + 255) & ~(size_t)255; return o;
  };
  u16*   Wt0   = (u16*)(ws + take((size_t)kG * kH * 2));   // 8 MB
  u16*   Wt1   = (u16*)(ws + take((size_t)kG * kH * 2));   // 8 MB
  u16*   Wob   = (u16*)(ws + take((size_t)kO * kH * 2));   // 0.5 MB
  float* bias0 = (float*)(ws + take((size_t)kG * 4));
  float* bias1 = (float*)(ws + take((size_t)kG * 4));
  float* cst   = (float*)(ws + take((size_t)kB * kH * 4)); // 2 MB
  const long HS = (long)kB * kH;
  u16* Hbuf = (u16*)(ws + off);
  const size_t havail = ws_size > off ? ws_size - off : 0;
  // Path A: keep full h-history (129 slices) and do one batched pred GEMM.
  // Path B fallback (small ws): 2-slice double buffer + per-step pred.
  const int nsl = (havail >= (size_t)(kT + 1) * HS * 2) ? (kT + 1) : 2;

  k_init<<<dim3(kB * kH / 256), dim3(256), 0, stream>>>(enc, cst, Hbuf);
  k_bias<<<dim3(kG / 256), dim3(256), 0, stream>>>(bih, bhh, Wih, bout, bias0, bias1);
  k_w0<<<dim3(kG), dim3(256), 0, stream>>>(Whh, Wt0);
  k_wo<<<dim3(kO * kH / 1024), dim3(256), 0, stream>>>(Wout, Wob);
  k_w1<<<dim3(256), dim3(256), 0, stream>>>(Wih, Wout, Whh, Wt1);

  for (int t = 0; t < kT; ++t) {
    const u16* Xp = Hbuf + (long)(t % nsl) * HS;
    u16*       Hn = Hbuf + (long)((t + 1) % nsl) * HS;
    k_step<<<dim3(kH / 32, kB / 64), dim3(256), 0, stream>>>(
        Xp, Hn, cst, t == 0 ? Wt0 : Wt1, t == 0 ? bias0 : bias1);
    if (nsl == 2)
      k_pred<<<dim3(kO / 128, kB / 64, 1), dim3(256), 0, stream>>>(
          Hbuf, HS, nsl, Wob, bout, out, t);
  }
  if (nsl != 2)
    k_pred<<<dim3(kO / 128, kB / 64, kT), dim3(256), 0, stream>>>(
        Hbuf, HS, nsl, Wob, bout, out, 0);
}